// Round 1
// baseline (2180.969 us; speedup 1.0000x reference)
//
#include <hip/hip_runtime.h>

#define N_NODES 50000
#define VOCAB   5000
#define HID     64
#define HEADS   4
#define NCLS    20
#define NGRAPH  128
#define N_EDGES 1600000
#define ETOT    (N_EDGES + N_NODES)

typedef __attribute__((ext_vector_type(8))) short short8;
typedef __attribute__((ext_vector_type(4))) float f32x4;

__device__ inline ushort f2bf(float x) {
  union { float f; unsigned u; } c; c.f = x;
  unsigned r = (c.u + 0x7fffu + ((c.u >> 16) & 1u)) >> 16;
  return (ushort)r;
}

// ---------------- fp32 -> bf16 weight convert ----------------
__global__ void cvt_bf16_kernel(const float* __restrict__ in, ushort* __restrict__ out, int n) {
  int i = blockIdx.x * blockDim.x + threadIdx.x;
  if (i < n) out[i] = f2bf(in[i]);
}

// ---------------- GEMM: D[M,64] = A[M,KT] * B[KT,64] (bf16 MFMA) ----------------
template<int KT>
__global__ __launch_bounds__(256) void gemm_kernel(const float* __restrict__ A,
    const ushort* __restrict__ B, float* __restrict__ D, int M) {
  __shared__ ushort As[64][40];   // +8 pad: 80B row stride, 16B aligned frags, conflict-free
  __shared__ ushort Bs[64][40];   // B stored transposed: Bs[col][k]
  int t = threadIdx.x;
  int wave = t >> 6, lane = t & 63;
  int lr = lane & 15, quad = lane >> 4;
  int rowBase = blockIdx.x * 64;
  f32x4 acc[4] = {{0,0,0,0},{0,0,0,0},{0,0,0,0},{0,0,0,0}};
  const int KSTEPS = (KT + 31) / 32;
  for (int ks = 0; ks < KSTEPS; ++ks) {
    int k0 = ks * 32;
    __syncthreads();
    // stage A tile 64x32 fp32 -> bf16 LDS (512 float4, 2 per thread)
    #pragma unroll
    for (int i = 0; i < 2; ++i) {
      int q = t + i * 256;
      int row = q >> 3, c4 = (q & 7) << 2;
      float4 v = make_float4(0.f, 0.f, 0.f, 0.f);
      int gr = rowBase + row;
      if (gr < M && (k0 + c4) < KT)
        v = *(const float4*)(A + (size_t)gr * KT + k0 + c4);
      ushort4 u;
      u.x = f2bf(v.x); u.y = f2bf(v.y); u.z = f2bf(v.z); u.w = f2bf(v.w);
      *(ushort4*)&As[row][c4] = u;
    }
    // stage B tile 32x64 bf16 (transposed into Bs[col][k]); 16B per thread
    {
      int e0 = t << 3;
      int k = e0 >> 6, c = e0 & 63;
      union { uint4 v; ushort u[8]; } w;
      w.v = make_uint4(0, 0, 0, 0);
      if (k0 + k < KT)
        w.v = *(const uint4*)(B + (size_t)(k0 + k) * 64 + c);
      #pragma unroll
      for (int j = 0; j < 8; ++j) Bs[c + j][k] = w.u[j];
    }
    __syncthreads();
    // A-frag: A[m=lane&15][k=quad*8+j]; B-frag: B[k=quad*8+j][n=lane&15]
    short8 af = *(short8*)&As[wave * 16 + lr][quad * 8];
    #pragma unroll
    for (int ct = 0; ct < 4; ++ct) {
      short8 bfr = *(short8*)&Bs[ct * 16 + lr][quad * 8];
      acc[ct] = __builtin_amdgcn_mfma_f32_16x16x32_bf16(af, bfr, acc[ct], 0, 0, 0);
    }
  }
  // C/D layout: col = lane&15, row = quad*4 + reg
  #pragma unroll
  for (int ct = 0; ct < 4; ++ct) {
    #pragma unroll
    for (int r = 0; r < 4; ++r) {
      int grow = rowBase + wave * 16 + quad * 4 + r;
      if (grow < M) D[(size_t)grow * 64 + ct * 16 + lr] = acc[ct][r];
    }
  }
}

// ---------------- attention coefficient dots ----------------
// H=4,C=16: alS[n,h] = sum_c h[n,h*16+c]*a_src[h*16+c]
__global__ void al_h4_kernel(const float* __restrict__ h, const float* __restrict__ a_src,
                             const float* __restrict__ a_dst, float* __restrict__ alS,
                             float* __restrict__ alD, int n) {
  int wid = (blockIdx.x * blockDim.x + threadIdx.x) >> 6;
  int lane = threadIdx.x & 63;
  if (wid >= n) return;
  float hv = h[(size_t)wid * 64 + lane];
  float s = hv * a_src[lane];
  float d = hv * a_dst[lane];
  #pragma unroll
  for (int off = 1; off < 16; off <<= 1) {
    s += __shfl_down(s, off, 16);
    d += __shfl_down(d, off, 16);
  }
  if ((lane & 15) == 0) {
    alS[wid * 4 + (lane >> 4)] = s;
    alD[wid * 4 + (lane >> 4)] = d;
  }
}

// H=1,C=64
__global__ void al_h1_kernel(const float* __restrict__ h, const float* __restrict__ a_src,
                             const float* __restrict__ a_dst, float* __restrict__ alS,
                             float* __restrict__ alD, int n) {
  int wid = (blockIdx.x * blockDim.x + threadIdx.x) >> 6;
  int lane = threadIdx.x & 63;
  if (wid >= n) return;
  float hv = h[(size_t)wid * 64 + lane];
  float s = hv * a_src[lane];
  float d = hv * a_dst[lane];
  #pragma unroll
  for (int off = 1; off < 64; off <<= 1) {
    s += __shfl_down(s, off, 64);
    d += __shfl_down(d, off, 64);
  }
  if (lane == 0) { alS[wid] = s; alD[wid] = d; }
}

// ---------------- CSR build (dst-sorted edges; self-loops are ids E..E+N-1) ----------------
__global__ void hist_kernel(const int* __restrict__ dstA, int* __restrict__ deg, int E, int Etot) {
  int i = blockIdx.x * blockDim.x + threadIdx.x;
  if (i >= Etot) return;
  int d = (i < E) ? dstA[i] : (i - E);
  atomicAdd(&deg[d], 1);
}

#define SCAN_T 1024
__global__ __launch_bounds__(SCAN_T) void scan_kernel(const int* __restrict__ deg,
                                                      int* __restrict__ indptr, int n) {
  __shared__ int buf[SCAN_T];
  __shared__ int s_run;
  int t = threadIdx.x;
  if (t == 0) s_run = 0;
  __syncthreads();
  for (int base = 0; base < n; base += SCAN_T) {
    int i = base + t;
    int v = (i < n) ? deg[i] : 0;
    buf[t] = v;
    __syncthreads();
    for (int off = 1; off < SCAN_T; off <<= 1) {
      int x = (t >= off) ? buf[t - off] : 0;
      __syncthreads();
      buf[t] += x;
      __syncthreads();
    }
    int incl = buf[t];
    int total = buf[SCAN_T - 1];
    if (i < n) indptr[i] = s_run + incl - v;  // exclusive scan
    __syncthreads();
    if (t == 0) s_run += total;
    __syncthreads();
  }
  if (t == 0) indptr[n] = s_run;
}

__global__ void scatter_kernel(const int* __restrict__ srcA, const int* __restrict__ dstA,
                               const int* __restrict__ indptr, int* __restrict__ fill,
                               int* __restrict__ srcs, int E, int Etot) {
  int i = blockIdx.x * blockDim.x + threadIdx.x;
  if (i >= Etot) return;
  int d, s;
  if (i < E) { d = dstA[i]; s = srcA[i]; } else { d = i - E; s = d; }
  int pos = indptr[d] + atomicAdd(&fill[d], 1);
  srcs[pos] = s;
}

// ---------------- per-dst online-softmax aggregation + bias + ELU ----------------
template<int H>
__global__ void agg_kernel(const float* __restrict__ h, const float* __restrict__ alS,
                           const float* __restrict__ alD, const int* __restrict__ indptr,
                           const int* __restrict__ srcs, const float* __restrict__ bias,
                           float* __restrict__ out, int n) {
  int wid = (blockIdx.x * blockDim.x + threadIdx.x) >> 6;
  int lane = threadIdx.x & 63;
  if (wid >= n) return;
  constexpr int C = 64 / H;
  int head = lane / C;
  float ald = alD[wid * H + head];
  int j0 = indptr[wid], j1 = indptr[wid + 1];
  float m = -3.0e38f, ssum = 0.f, acc = 0.f;
  for (int j = j0; j < j1; ++j) {
    int s = srcs[j];
    float e = alS[s * H + head] + ald;
    e = e > 0.f ? e : 0.2f * e;              // leaky_relu(0.2)
    float hv = h[(size_t)s * 64 + lane];
    float mn = fmaxf(m, e);
    float sc = __expf(m - mn);
    float p  = __expf(e - mn);
    ssum = ssum * sc + p;
    acc  = acc * sc + p * hv;
    m = mn;
  }
  float o = acc / (ssum + 1e-16f) + bias[lane];
  o = o > 0.f ? o : __expf(o) - 1.f;         // ELU
  out[(size_t)wid * 64 + lane] = o;
}

// ---------------- pooling ----------------
__global__ void cnt_kernel(const int* __restrict__ batch, int* __restrict__ cnts, int n) {
  int i = blockIdx.x * blockDim.x + threadIdx.x;
  if (i < n) atomicAdd(&cnts[batch[i]], 1);
}

__global__ void pool_kernel(const float* __restrict__ h, const int* __restrict__ batch,
                            float* __restrict__ pooled, int n) {
  int wid = (blockIdx.x * blockDim.x + threadIdx.x) >> 6;
  int lane = threadIdx.x & 63;
  int n0 = wid * 64;
  if (n0 >= n) return;
  int n1 = min(n0 + 64, n);
  int g_cur = batch[n0];
  float acc = 0.f;
  for (int i = n0; i < n1; ++i) {
    int g = batch[i];
    if (g != g_cur) {
      atomicAdd(&pooled[g_cur * 64 + lane], acc);
      acc = 0.f; g_cur = g;
    }
    acc += h[(size_t)i * 64 + lane];
  }
  atomicAdd(&pooled[g_cur * 64 + lane], acc);
}

// ---------------- classifier + log_softmax ----------------
__global__ __launch_bounds__(128) void cls_kernel(const float* __restrict__ pooled,
    const int* __restrict__ cnts, const float* __restrict__ Wc,
    const float* __restrict__ bc, float* __restrict__ out) {
  int g = threadIdx.x;
  if (g >= NGRAPH) return;
  float inv = 1.f / fmaxf((float)cnts[g], 1.f);
  float p[64];
  #pragma unroll
  for (int k = 0; k < 64; ++k) p[k] = pooled[g * 64 + k] * inv;
  float lg[NCLS];
  float mx = -3.0e38f;
  #pragma unroll
  for (int c = 0; c < NCLS; ++c) {
    float v = bc[c];
    for (int k = 0; k < 64; ++k) v += p[k] * Wc[k * NCLS + c];
    lg[c] = v;
    mx = fmaxf(mx, v);
  }
  float se = 0.f;
  #pragma unroll
  for (int c = 0; c < NCLS; ++c) se += expf(lg[c] - mx);
  float ls = logf(se);
  #pragma unroll
  for (int c = 0; c < NCLS; ++c) out[g * NCLS + c] = lg[c] - mx - ls;
}

extern "C" void kernel_launch(void* const* d_in, const int* in_sizes, int n_in,
                              void* d_out, int out_size, void* d_ws, size_t ws_size,
                              hipStream_t stream) {
  const float* x      = (const float*)d_in[0];
  const int*   ei     = (const int*)d_in[1];    // [2,E]: row0 src, row1 dst
  const int*   batch  = (const int*)d_in[2];
  const float* W1     = (const float*)d_in[3];
  const float* a_src1 = (const float*)d_in[4];
  const float* a_dst1 = (const float*)d_in[5];
  const float* b1     = (const float*)d_in[6];
  const float* W2     = (const float*)d_in[7];
  const float* a_src2 = (const float*)d_in[8];
  const float* a_dst2 = (const float*)d_in[9];
  const float* b2     = (const float*)d_in[10];
  const float* Wc     = (const float*)d_in[11];
  const float* bc     = (const float*)d_in[12];
  float* out = (float*)d_out;

  const int* srcA = ei;
  const int* dstA = ei + N_EDGES;

  char* ws = (char*)d_ws;
  size_t off = 0;
  auto alloc = [&](size_t bytes) -> void* {
    void* p = ws + off;
    off = (off + bytes + 255) & ~(size_t)255;
    return p;
  };
  float* bufA   = (float*)alloc((size_t)N_NODES * 64 * 4);  // h1 / h2
  float* bufB   = (float*)alloc((size_t)N_NODES * 64 * 4);  // h1b / h2b
  float* alS1   = (float*)alloc((size_t)N_NODES * 4 * 4);
  float* alD1   = (float*)alloc((size_t)N_NODES * 4 * 4);
  float* alS2   = (float*)alloc((size_t)N_NODES * 4);
  float* alD2   = (float*)alloc((size_t)N_NODES * 4);
  ushort* w1bf  = (ushort*)alloc((size_t)VOCAB * 64 * 2);
  ushort* w2bf  = (ushort*)alloc((size_t)64 * 64 * 2);
  int* deg      = (int*)alloc((size_t)N_NODES * 4);
  int* fill     = (int*)alloc((size_t)N_NODES * 4);
  int* indptr   = (int*)alloc((size_t)(N_NODES + 1) * 4);
  int* srcs     = (int*)alloc((size_t)ETOT * 4);
  float* pooled = (float*)alloc((size_t)NGRAPH * 64 * 4);
  int* cnts     = (int*)alloc((size_t)NGRAPH * 4);

  // zero-init (ws is poisoned 0xAA before every call)
  hipMemsetAsync(deg, 0, (size_t)N_NODES * 4, stream);
  hipMemsetAsync(fill, 0, (size_t)N_NODES * 4, stream);
  hipMemsetAsync(pooled, 0, (size_t)NGRAPH * 64 * 4, stream);
  hipMemsetAsync(cnts, 0, (size_t)NGRAPH * 4, stream);

  // weights -> bf16
  cvt_bf16_kernel<<<(VOCAB * 64 + 255) / 256, 256, 0, stream>>>(W1, w1bf, VOCAB * 64);
  cvt_bf16_kernel<<<(64 * 64 + 255) / 256, 256, 0, stream>>>(W2, w2bf, 64 * 64);

  // CSR build (shared by both layers)
  int egrid = (ETOT + 255) / 256;
  hist_kernel<<<egrid, 256, 0, stream>>>(dstA, deg, N_EDGES, ETOT);
  scan_kernel<<<1, SCAN_T, 0, stream>>>(deg, indptr, N_NODES);
  scatter_kernel<<<egrid, 256, 0, stream>>>(srcA, dstA, indptr, fill, srcs, N_EDGES, ETOT);

  int nwaveBlocks = (N_NODES * 64 + 255) / 256;  // one wave per node

  // ---- layer 1 ----
  gemm_kernel<VOCAB><<<(N_NODES + 63) / 64, 256, 0, stream>>>(x, w1bf, bufA, N_NODES);
  al_h4_kernel<<<nwaveBlocks, 256, 0, stream>>>(bufA, a_src1, a_dst1, alS1, alD1, N_NODES);
  agg_kernel<4><<<nwaveBlocks, 256, 0, stream>>>(bufA, alS1, alD1, indptr, srcs, b1, bufB, N_NODES);

  // ---- layer 2 ----
  gemm_kernel<64><<<(N_NODES + 63) / 64, 256, 0, stream>>>(bufB, w2bf, bufA, N_NODES);
  al_h1_kernel<<<nwaveBlocks, 256, 0, stream>>>(bufA, a_src2, a_dst2, alS2, alD2, N_NODES);
  agg_kernel<1><<<nwaveBlocks, 256, 0, stream>>>(bufA, alS2, alD2, indptr, srcs, b2, bufB, N_NODES);

  // ---- pool + classifier ----
  cnt_kernel<<<(N_NODES + 255) / 256, 256, 0, stream>>>(batch, cnts, N_NODES);
  pool_kernel<<<((N_NODES + 63) / 64 * 64 + 255) / 256, 256, 0, stream>>>(bufB, batch, pooled, N_NODES);
  cls_kernel<<<1, 128, 0, stream>>>(pooled, cnts, Wc, bc, out);
}

// Round 2
// 1994.577 us; speedup vs baseline: 1.0934x; 1.0934x over previous
//
#include <hip/hip_runtime.h>

#define N_NODES 50000
#define VOCAB   5000
#define KPAD1   5024
#define HID     64
#define HEADS   4
#define NCLS    20
#define NGRAPH  128
#define N_EDGES 1600000
#define ETOT    (N_EDGES + N_NODES)

typedef __attribute__((ext_vector_type(8))) short short8;
typedef __attribute__((ext_vector_type(4))) float f32x4;

__device__ inline ushort f2bf(float x) {
  union { float f; unsigned u; } c; c.f = x;
  unsigned r = (c.u + 0x7fffu + ((c.u >> 16) & 1u)) >> 16;
  return (ushort)r;
}

// ---------------- weight convert + transpose: Bt[n][k] = bf16(W[k][n]) ----------------
__global__ void cvtT_kernel(const float* __restrict__ W, ushort* __restrict__ Bt,
                            int K, int KP) {
  int i = blockIdx.x * blockDim.x + threadIdx.x;
  if (i >= 64 * KP) return;
  int n = i / KP, k = i - n * KP;
  Bt[i] = (k < K) ? f2bf(W[(size_t)k * 64 + n]) : (ushort)0;
}

// ---------------- streaming GEMM: D[M,64] = A[M,KT] * Bt^T, no LDS, no barriers ----------------
// one wave owns 16 rows; A-frag loaded direct from global (lane: 32B contiguous),
// B-frag from pre-transposed bf16 Bt[64][KPAD] (L2-resident).
template<int KT, int KP>
__global__ __launch_bounds__(256) void gemm_stream(const float* __restrict__ A,
    const ushort* __restrict__ Bt, float* __restrict__ D, int M) {
  int gt = blockIdx.x * 256 + threadIdx.x;
  int gw = gt >> 6, lane = gt & 63;
  int lr = lane & 15, quad = lane >> 4;
  int m0 = gw * 16;
  if (m0 >= M) return;
  const float*  ap = A  + (size_t)(m0 + lr) * KT + quad * 8;
  const ushort* bp = Bt + (size_t)lr * KP + quad * 8;
  f32x4 acc[4] = {{0,0,0,0},{0,0,0,0},{0,0,0,0},{0,0,0,0}};
  constexpr int KF = (KT / 32) * 32;
  #pragma unroll 2
  for (int k0 = 0; k0 < KF; k0 += 32) {
    float4 v0 = *(const float4*)(ap + k0);
    float4 v1 = *(const float4*)(ap + k0 + 4);
    short8 b0 = *(const short8*)(bp + k0);
    short8 b1 = *(const short8*)(bp + 16 * KP + k0);
    short8 b2 = *(const short8*)(bp + 32 * KP + k0);
    short8 b3 = *(const short8*)(bp + 48 * KP + k0);
    short8 af;
    af[0] = (short)f2bf(v0.x); af[1] = (short)f2bf(v0.y);
    af[2] = (short)f2bf(v0.z); af[3] = (short)f2bf(v0.w);
    af[4] = (short)f2bf(v1.x); af[5] = (short)f2bf(v1.y);
    af[6] = (short)f2bf(v1.z); af[7] = (short)f2bf(v1.w);
    acc[0] = __builtin_amdgcn_mfma_f32_16x16x32_bf16(af, b0, acc[0], 0, 0, 0);
    acc[1] = __builtin_amdgcn_mfma_f32_16x16x32_bf16(af, b1, acc[1], 0, 0, 0);
    acc[2] = __builtin_amdgcn_mfma_f32_16x16x32_bf16(af, b2, acc[2], 0, 0, 0);
    acc[3] = __builtin_amdgcn_mfma_f32_16x16x32_bf16(af, b3, acc[3], 0, 0, 0);
  }
  if (KT % 32) {  // tail: only quad 0 has valid k (KT%32==8 for VOCAB)
    int k0 = KF;
    float4 v0 = make_float4(0,0,0,0), v1 = make_float4(0,0,0,0);
    if (quad == 0) { v0 = *(const float4*)(ap + k0); v1 = *(const float4*)(ap + k0 + 4); }
    short8 b0 = *(const short8*)(bp + k0);
    short8 b1 = *(const short8*)(bp + 16 * KP + k0);
    short8 b2 = *(const short8*)(bp + 32 * KP + k0);
    short8 b3 = *(const short8*)(bp + 48 * KP + k0);
    short8 af;
    af[0] = (short)f2bf(v0.x); af[1] = (short)f2bf(v0.y);
    af[2] = (short)f2bf(v0.z); af[3] = (short)f2bf(v0.w);
    af[4] = (short)f2bf(v1.x); af[5] = (short)f2bf(v1.y);
    af[6] = (short)f2bf(v1.z); af[7] = (short)f2bf(v1.w);
    acc[0] = __builtin_amdgcn_mfma_f32_16x16x32_bf16(af, b0, acc[0], 0, 0, 0);
    acc[1] = __builtin_amdgcn_mfma_f32_16x16x32_bf16(af, b1, acc[1], 0, 0, 0);
    acc[2] = __builtin_amdgcn_mfma_f32_16x16x32_bf16(af, b2, acc[2], 0, 0, 0);
    acc[3] = __builtin_amdgcn_mfma_f32_16x16x32_bf16(af, b3, acc[3], 0, 0, 0);
  }
  // C/D: col = ct*16 + (lane&15), row = quad*4 + reg
  #pragma unroll
  for (int ct = 0; ct < 4; ++ct)
    #pragma unroll
    for (int r = 0; r < 4; ++r)
      D[(size_t)(m0 + quad * 4 + r) * 64 + ct * 16 + lr] = acc[ct][r];
}

// ---------------- attention coefficient dots ----------------
__global__ void al_h4_kernel(const float* __restrict__ h, const float* __restrict__ a_src,
                             const float* __restrict__ a_dst, float* __restrict__ alS,
                             float* __restrict__ alD, int n) {
  int wid = (blockIdx.x * blockDim.x + threadIdx.x) >> 6;
  int lane = threadIdx.x & 63;
  if (wid >= n) return;
  float hv = h[(size_t)wid * 64 + lane];
  float s = hv * a_src[lane];
  float d = hv * a_dst[lane];
  #pragma unroll
  for (int off = 1; off < 16; off <<= 1) {
    s += __shfl_down(s, off, 16);
    d += __shfl_down(d, off, 16);
  }
  if ((lane & 15) == 0) {
    alS[wid * 4 + (lane >> 4)] = s;
    alD[wid * 4 + (lane >> 4)] = d;
  }
}

__global__ void al_h1_kernel(const float* __restrict__ h, const float* __restrict__ a_src,
                             const float* __restrict__ a_dst, float* __restrict__ alS,
                             float* __restrict__ alD, int n) {
  int wid = (blockIdx.x * blockDim.x + threadIdx.x) >> 6;
  int lane = threadIdx.x & 63;
  if (wid >= n) return;
  float hv = h[(size_t)wid * 64 + lane];
  float s = hv * a_src[lane];
  float d = hv * a_dst[lane];
  #pragma unroll
  for (int off = 1; off < 64; off <<= 1) {
    s += __shfl_down(s, off, 64);
    d += __shfl_down(d, off, 64);
  }
  if (lane == 0) { alS[wid] = s; alD[wid] = d; }
}

// ---------------- CSR build ----------------
__global__ void hist_kernel(const int* __restrict__ dstA, int* __restrict__ deg, int E, int Etot) {
  int i = blockIdx.x * blockDim.x + threadIdx.x;
  if (i >= Etot) return;
  int d = (i < E) ? dstA[i] : (i - E);
  atomicAdd(&deg[d], 1);
}

// wave-shuffle based single-block scan (3 barriers per 1024-chunk)
__global__ __launch_bounds__(1024) void scan_kernel(const int* __restrict__ deg,
                                                    int* __restrict__ indptr, int n) {
  __shared__ int wsum[16];
  __shared__ int carry;
  int t = threadIdx.x, w = t >> 6, lane = t & 63;
  if (t == 0) carry = 0;
  __syncthreads();
  for (int base = 0; base < n; base += 1024) {
    int i = base + t;
    int v = (i < n) ? deg[i] : 0;
    int x = v;
    #pragma unroll
    for (int off = 1; off < 64; off <<= 1) {
      int y = __shfl_up(x, off, 64);
      if (lane >= off) x += y;
    }
    if (lane == 63) wsum[w] = x;
    __syncthreads();
    if (w == 0 && lane < 16) {
      int y = wsum[lane];
      #pragma unroll
      for (int off = 1; off < 16; off <<= 1) {
        int z = __shfl_up(y, off, 16);
        if (lane >= off) y += z;
      }
      wsum[lane] = y;
    }
    __syncthreads();
    int incl = x + (w > 0 ? wsum[w - 1] : 0) + carry;
    if (i < n) indptr[i] = incl - v;  // exclusive
    __syncthreads();
    if (t == 1023) carry = incl;
    __syncthreads();
  }
  if (t == 0) indptr[n] = carry;
}

__global__ void scatter_kernel(const int* __restrict__ srcA, const int* __restrict__ dstA,
                               const int* __restrict__ indptr, int* __restrict__ fill,
                               int* __restrict__ srcs, int E, int Etot) {
  int i = blockIdx.x * blockDim.x + threadIdx.x;
  if (i >= Etot) return;
  int d, s;
  if (i < E) { d = dstA[i]; s = srcA[i]; } else { d = i - E; s = d; }
  int pos = indptr[d] + atomicAdd(&fill[d], 1);
  srcs[pos] = s;
}

// ---------------- per-dst online-softmax aggregation, 4-edge batches + index prefetch ----------------
template<int H>
__global__ __launch_bounds__(256) void agg_kernel(const float* __restrict__ h,
    const float* __restrict__ alS, const float* __restrict__ alD,
    const int* __restrict__ indptr, const int* __restrict__ srcs,
    const float* __restrict__ bias, float* __restrict__ out, int n) {
  int wid = (blockIdx.x * blockDim.x + threadIdx.x) >> 6;
  int lane = threadIdx.x & 63;
  if (wid >= n) return;
  constexpr int C = 64 / H;
  int head = lane / C;
  float ald = alD[wid * H + head];
  int j0 = indptr[wid], j1 = indptr[wid + 1];
  float m = -3.0e38f, ssum = 0.f, acc = 0.f;
  // prefetch first batch (srcs padded by +16 ints; garbage entries are use-guarded)
  int p0 = srcs[j0], p1 = srcs[j0 + 1], p2 = srcs[j0 + 2], p3 = srcs[j0 + 3];
  for (int j = j0; j < j1; j += 4) {
    int rem = j1 - j;
    int s0 = p0;
    int s1 = (rem > 1) ? p1 : p0;
    int s2 = (rem > 2) ? p2 : p0;
    int s3 = (rem > 3) ? p3 : p0;
    int jn = j + 4;
    if (jn < j1) { p0 = srcs[jn]; p1 = srcs[jn + 1]; p2 = srcs[jn + 2]; p3 = srcs[jn + 3]; }
    float e0 = alS[s0 * H + head] + ald;
    float e1 = alS[s1 * H + head] + ald;
    float e2 = alS[s2 * H + head] + ald;
    float e3 = alS[s3 * H + head] + ald;
    float h0 = h[(size_t)s0 * 64 + lane];
    float h1 = h[(size_t)s1 * 64 + lane];
    float h2 = h[(size_t)s2 * 64 + lane];
    float h3 = h[(size_t)s3 * 64 + lane];
    e0 = e0 > 0.f ? e0 : 0.2f * e0;
    e1 = e1 > 0.f ? e1 : 0.2f * e1;
    e2 = e2 > 0.f ? e2 : 0.2f * e2;
    e3 = e3 > 0.f ? e3 : 0.2f * e3;
    e1 = (rem > 1) ? e1 : -3.0e38f;
    e2 = (rem > 2) ? e2 : -3.0e38f;
    e3 = (rem > 3) ? e3 : -3.0e38f;
    float cm = fmaxf(fmaxf(e0, e1), fmaxf(e2, e3));
    float mn = fmaxf(m, cm);
    float sc = __expf(m - mn);
    float q0 = __expf(e0 - mn), q1 = __expf(e1 - mn);
    float q2 = __expf(e2 - mn), q3 = __expf(e3 - mn);
    ssum = ssum * sc + q0 + q1 + q2 + q3;
    acc  = acc  * sc + q0 * h0 + q1 * h1 + q2 * h2 + q3 * h3;
    m = mn;
  }
  float o = acc / (ssum + 1e-16f) + bias[lane];
  o = o > 0.f ? o : __expf(o) - 1.f;  // ELU
  out[(size_t)wid * 64 + lane] = o;
}

// ---------------- pooling ----------------
__global__ void cnt_kernel(const int* __restrict__ batch, int* __restrict__ cnts, int n) {
  int i = blockIdx.x * blockDim.x + threadIdx.x;
  if (i < n) atomicAdd(&cnts[batch[i]], 1);
}

__global__ void pool_kernel(const float* __restrict__ h, const int* __restrict__ batch,
                            float* __restrict__ pooled, int n) {
  int wid = (blockIdx.x * blockDim.x + threadIdx.x) >> 6;
  int lane = threadIdx.x & 63;
  int n0 = wid * 64;
  if (n0 >= n) return;
  int n1 = min(n0 + 64, n);
  int g = batch[min(n0 + lane, n - 1)];
  int gf = __shfl(g, 0), gl = __shfl(g, 63);
  if (gf == gl && n1 == n0 + 64) {  // whole chunk in one graph: pipelined fast path
    float a = 0.f;
    #pragma unroll 8
    for (int i = n0; i < n1; ++i) a += h[(size_t)i * 64 + lane];
    atomicAdd(&pooled[gf * 64 + lane], a);
  } else {
    int g_cur = batch[n0];
    float a = 0.f;
    for (int i = n0; i < n1; ++i) {
      int gg = batch[i];
      if (gg != g_cur) {
        atomicAdd(&pooled[g_cur * 64 + lane], a);
        a = 0.f; g_cur = gg;
      }
      a += h[(size_t)i * 64 + lane];
    }
    atomicAdd(&pooled[g_cur * 64 + lane], a);
  }
}

// ---------------- classifier + log_softmax ----------------
__global__ __launch_bounds__(128) void cls_kernel(const float* __restrict__ pooled,
    const int* __restrict__ cnts, const float* __restrict__ Wc,
    const float* __restrict__ bc, float* __restrict__ out) {
  int g = threadIdx.x;
  if (g >= NGRAPH) return;
  float inv = 1.f / fmaxf((float)cnts[g], 1.f);
  float p[64];
  #pragma unroll
  for (int k = 0; k < 64; ++k) p[k] = pooled[g * 64 + k] * inv;
  float lg[NCLS];
  float mx = -3.0e38f;
  #pragma unroll
  for (int c = 0; c < NCLS; ++c) {
    float v = bc[c];
    for (int k = 0; k < 64; ++k) v += p[k] * Wc[k * NCLS + c];
    lg[c] = v;
    mx = fmaxf(mx, v);
  }
  float se = 0.f;
  #pragma unroll
  for (int c = 0; c < NCLS; ++c) se += expf(lg[c] - mx);
  float ls = logf(se);
  #pragma unroll
  for (int c = 0; c < NCLS; ++c) out[g * NCLS + c] = lg[c] - mx - ls;
}

extern "C" void kernel_launch(void* const* d_in, const int* in_sizes, int n_in,
                              void* d_out, int out_size, void* d_ws, size_t ws_size,
                              hipStream_t stream) {
  const float* x      = (const float*)d_in[0];
  const int*   ei     = (const int*)d_in[1];
  const int*   batch  = (const int*)d_in[2];
  const float* W1     = (const float*)d_in[3];
  const float* a_src1 = (const float*)d_in[4];
  const float* a_dst1 = (const float*)d_in[5];
  const float* b1     = (const float*)d_in[6];
  const float* W2     = (const float*)d_in[7];
  const float* a_src2 = (const float*)d_in[8];
  const float* a_dst2 = (const float*)d_in[9];
  const float* b2     = (const float*)d_in[10];
  const float* Wc     = (const float*)d_in[11];
  const float* bc     = (const float*)d_in[12];
  float* out = (float*)d_out;

  const int* srcA = ei;
  const int* dstA = ei + N_EDGES;

  char* ws = (char*)d_ws;
  size_t off = 0;
  auto alloc = [&](size_t bytes) -> void* {
    void* p = ws + off;
    off = (off + bytes + 255) & ~(size_t)255;
    return p;
  };
  float* bufA   = (float*)alloc((size_t)N_NODES * 64 * 4);
  float* bufB   = (float*)alloc((size_t)N_NODES * 64 * 4);
  float* alS1   = (float*)alloc((size_t)N_NODES * 4 * 4);
  float* alD1   = (float*)alloc((size_t)N_NODES * 4 * 4);
  float* alS2   = (float*)alloc((size_t)N_NODES * 4);
  float* alD2   = (float*)alloc((size_t)N_NODES * 4);
  ushort* w1t   = (ushort*)alloc((size_t)64 * KPAD1 * 2);
  ushort* w2t   = (ushort*)alloc((size_t)64 * 64 * 2);
  int* deg      = (int*)alloc((size_t)N_NODES * 4);
  int* fill     = (int*)alloc((size_t)N_NODES * 4);
  int* indptr   = (int*)alloc((size_t)(N_NODES + 1) * 4);
  int* srcs     = (int*)alloc((size_t)(ETOT + 16) * 4);  // +16 pad for prefetch
  float* pooled = (float*)alloc((size_t)NGRAPH * 64 * 4);
  int* cnts     = (int*)alloc((size_t)NGRAPH * 4);

  hipMemsetAsync(deg, 0, (size_t)N_NODES * 4, stream);
  hipMemsetAsync(fill, 0, (size_t)N_NODES * 4, stream);
  hipMemsetAsync(pooled, 0, (size_t)NGRAPH * 64 * 4, stream);
  hipMemsetAsync(cnts, 0, (size_t)NGRAPH * 4, stream);

  // weights -> bf16 transposed
  cvtT_kernel<<<(64 * KPAD1 + 255) / 256, 256, 0, stream>>>(W1, w1t, VOCAB, KPAD1);
  cvtT_kernel<<<(64 * 64 + 255) / 256, 256, 0, stream>>>(W2, w2t, 64, 64);

  // CSR build (shared by both layers)
  int egrid = (ETOT + 255) / 256;
  hist_kernel<<<egrid, 256, 0, stream>>>(dstA, deg, N_EDGES, ETOT);
  scan_kernel<<<1, 1024, 0, stream>>>(deg, indptr, N_NODES);
  scatter_kernel<<<egrid, 256, 0, stream>>>(srcA, dstA, indptr, fill, srcs, N_EDGES, ETOT);

  int nwaveBlocks = (N_NODES * 64 + 255) / 256;
  int gemmBlocks = ((N_NODES + 15) / 16 + 3) / 4;

  // ---- layer 1 ----
  gemm_stream<VOCAB, KPAD1><<<gemmBlocks, 256, 0, stream>>>(x, w1t, bufA, N_NODES);
  al_h4_kernel<<<nwaveBlocks, 256, 0, stream>>>(bufA, a_src1, a_dst1, alS1, alD1, N_NODES);
  agg_kernel<4><<<nwaveBlocks, 256, 0, stream>>>(bufA, alS1, alD1, indptr, srcs, b1, bufB, N_NODES);

  // ---- layer 2 ----
  gemm_stream<64, 64><<<gemmBlocks, 256, 0, stream>>>(bufB, w2t, bufA, N_NODES);
  al_h1_kernel<<<nwaveBlocks, 256, 0, stream>>>(bufA, a_src2, a_dst2, alS2, alD2, N_NODES);
  agg_kernel<1><<<nwaveBlocks, 256, 0, stream>>>(bufA, alS2, alD2, indptr, srcs, b2, bufB, N_NODES);

  // ---- pool + classifier ----
  cnt_kernel<<<(N_NODES + 255) / 256, 256, 0, stream>>>(batch, cnts, N_NODES);
  pool_kernel<<<((N_NODES + 63) / 64 * 64 + 255) / 256, 256, 0, stream>>>(bufB, batch, pooled, N_NODES);
  cls_kernel<<<1, 128, 0, stream>>>(pooled, cnts, Wc, bc, out);
}